// Round 1
// baseline (628.271 us; speedup 1.0000x reference)
//
#include <hip/hip_runtime.h>

// GraphSAGE: 2x SAGEConv(mean) + Linear + softmax. fp32 throughout.
// Pipeline: CSR build (count/scan/fill) -> [aggregate -> fused GEMM+ReLU] x2 -> out+softmax.

__global__ void count_kernel(const int* __restrict__ dst, int* __restrict__ cnt, int E, int N) {
    int e = blockIdx.x * blockDim.x + threadIdx.x;
    if (e < E) {
        int d = dst[e];
        if ((unsigned)d < (unsigned)N) atomicAdd(&cnt[d], 1);
    }
}

// Single-block exclusive scan over n ints (n ~ 50k: ~49 chunks of 1024).
__global__ void scan_kernel(const int* __restrict__ cnt, int* __restrict__ off, int n) {
    __shared__ int sdata[1024];
    __shared__ int running;
    if (threadIdx.x == 0) running = 0;
    __syncthreads();
    for (int base = 0; base < n; base += 1024) {
        int i = base + (int)threadIdx.x;
        int v = (i < n) ? cnt[i] : 0;
        sdata[threadIdx.x] = v;
        __syncthreads();
        for (int ofs = 1; ofs < 1024; ofs <<= 1) {
            int t = (threadIdx.x >= (unsigned)ofs) ? sdata[threadIdx.x - ofs] : 0;
            __syncthreads();
            sdata[threadIdx.x] += t;
            __syncthreads();
        }
        int incl = sdata[threadIdx.x];
        int total = sdata[1023];
        if (i < n) off[i] = running + incl - v;
        __syncthreads();                 // everyone reads `running` before update
        if (threadIdx.x == 0) running += total;
        __syncthreads();
    }
    if (threadIdx.x == 0) off[n] = running;
}

__global__ void fill_kernel(const int* __restrict__ src, const int* __restrict__ dstp,
                            const int* __restrict__ off, int* __restrict__ cursor,
                            int* __restrict__ csr, int E, int N) {
    int e = blockIdx.x * blockDim.x + threadIdx.x;
    if (e < E) {
        int d = dstp[e];
        int s = src[e];
        if ((unsigned)d < (unsigned)N) {
            int pos = atomicAdd(&cursor[d], 1);
            csr[off[d] + pos] = ((unsigned)s < (unsigned)N) ? s : 0;
        }
    }
}

// Mean aggregation: 32 lanes per node, float4 per lane (128 feats).
__global__ void aggregate_kernel(const float* __restrict__ h, const int* __restrict__ off,
                                 const int* __restrict__ csr, float* __restrict__ agg, int N) {
    int t = blockIdx.x * blockDim.x + threadIdx.x;
    int node = t >> 5;
    int lane = t & 31;
    if (node >= N) return;
    int s0 = off[node], s1 = off[node + 1];
    float4 acc = make_float4(0.f, 0.f, 0.f, 0.f);
    const float4* h4 = (const float4*)h;
    for (int e = s0; e < s1; ++e) {
        int s = csr[e];
        float4 v = h4[(size_t)s * 32 + lane];
        acc.x += v.x; acc.y += v.y; acc.z += v.z; acc.w += v.w;
    }
    float inv = 1.0f / (float)max(s1 - s0, 1);
    ((float4*)agg)[(size_t)node * 32 + lane] =
        make_float4(acc.x * inv, acc.y * inv, acc.z * inv, acc.w * inv);
}

// hout = relu(agg @ Wl + hin @ Wr + b). Block: 16 nodes x 128 cols, 256 threads.
// Thread: column j for 8 nodes; LDS feature reads are wave-broadcast float4s.
__global__ __launch_bounds__(256) void sage_linear_kernel(
        const float* __restrict__ agg, const float* __restrict__ hin,
        const float* __restrict__ Wl, const float* __restrict__ Wr,
        const float* __restrict__ b, float* __restrict__ hout, int N) {
    __shared__ float sAgg[16][128];
    __shared__ float sH[16][128];
    int node0 = blockIdx.x * 16;
    for (int i = threadIdx.x; i < 16 * 128; i += 256) {
        int nn = i >> 7, ff = i & 127;
        int node = node0 + nn;
        float a = 0.f, hh = 0.f;
        if (node < N) { a = agg[(size_t)node * 128 + ff]; hh = hin[(size_t)node * 128 + ff]; }
        sAgg[nn][ff] = a;
        sH[nn][ff] = hh;
    }
    __syncthreads();
    int j = threadIdx.x & 127;
    int g = threadIdx.x >> 7;   // node half: 0 -> nodes 0..7, 1 -> nodes 8..15
    float acc[8];
    float bj = b[j];
#pragma unroll
    for (int q = 0; q < 8; ++q) acc[q] = bj;
    for (int k4 = 0; k4 < 32; ++k4) {
        float wl[4], wr[4];
#pragma unroll
        for (int u = 0; u < 4; ++u) {
            wl[u] = Wl[(k4 * 4 + u) * 128 + j];
            wr[u] = Wr[(k4 * 4 + u) * 128 + j];
        }
#pragma unroll
        for (int q = 0; q < 8; ++q) {
            int nn = g * 8 + q;
            float4 a = ((const float4*)sAgg[nn])[k4];
            float4 hh = ((const float4*)sH[nn])[k4];
            acc[q] += a.x * wl[0] + a.y * wl[1] + a.z * wl[2] + a.w * wl[3]
                    + hh.x * wr[0] + hh.y * wr[1] + hh.z * wr[2] + hh.w * wr[3];
        }
    }
#pragma unroll
    for (int q = 0; q < 8; ++q) {
        int node = node0 + g * 8 + q;
        if (node < N) hout[(size_t)node * 128 + j] = fmaxf(acc[q], 0.f);
    }
}

// out = softmax(h @ Wout + bout), one wave per node, lane = output column (64).
__global__ void out_kernel(const float* __restrict__ h, const float* __restrict__ W,
                           const float* __restrict__ b, float* __restrict__ out, int N) {
    int gt = blockIdx.x * blockDim.x + threadIdx.x;
    int node = gt >> 6;
    int lane = gt & 63;
    if (node >= N) return;
    float acc = b[lane];
    const float4* h4 = (const float4*)(h + (size_t)node * 128);
    for (int k4 = 0; k4 < 32; ++k4) {
        float4 hv = h4[k4];
        acc += hv.x * W[(k4 * 4 + 0) * 64 + lane]
             + hv.y * W[(k4 * 4 + 1) * 64 + lane]
             + hv.z * W[(k4 * 4 + 2) * 64 + lane]
             + hv.w * W[(k4 * 4 + 3) * 64 + lane];
    }
    float m = acc;
#pragma unroll
    for (int o = 32; o; o >>= 1) m = fmaxf(m, __shfl_xor(m, o, 64));
    float e = __expf(acc - m);
    float s = e;
#pragma unroll
    for (int o = 32; o; o >>= 1) s += __shfl_xor(s, o, 64);
    out[(size_t)node * 64 + lane] = e / s;
}

extern "C" void kernel_launch(void* const* d_in, const int* in_sizes, int n_in,
                              void* d_out, int out_size, void* d_ws, size_t ws_size,
                              hipStream_t stream) {
    const float* x    = (const float*)d_in[0];
    const int*   ei   = (const int*)d_in[1];
    const float* Wl0  = (const float*)d_in[2];
    const float* Wr0  = (const float*)d_in[3];
    const float* b0   = (const float*)d_in[4];
    const float* Wl1  = (const float*)d_in[5];
    const float* Wr1  = (const float*)d_in[6];
    const float* b1   = (const float*)d_in[7];
    const float* Wout = (const float*)d_in[8];
    const float* bout = (const float*)d_in[9];

    int N = in_sizes[0] / 128;
    int E = in_sizes[1] / 2;
    const int* src = ei;
    const int* dst = ei + E;

    // Workspace carve-out (256B aligned): cnt, cursor, off, csr, agg, h0, h1 (~81 MB).
    char* p = (char*)d_ws;
    auto alloc = [&](size_t bytes) -> char* {
        char* r = p;
        p += (bytes + 255) & ~(size_t)255;
        return r;
    };
    int*   cnt    = (int*)alloc((size_t)N * 4);
    int*   cursor = (int*)alloc((size_t)N * 4);
    int*   off    = (int*)alloc((size_t)(N + 1) * 4);
    int*   csr    = (int*)alloc((size_t)E * 4);
    float* agg    = (float*)alloc((size_t)N * 128 * 4);
    float* h0     = (float*)alloc((size_t)N * 128 * 4);
    float* h1     = (float*)alloc((size_t)N * 128 * 4);

    hipMemsetAsync(cnt, 0, (size_t)N * 4, stream);
    hipMemsetAsync(cursor, 0, (size_t)N * 4, stream);

    int eb = (E + 255) / 256;
    count_kernel<<<eb, 256, 0, stream>>>(dst, cnt, E, N);
    scan_kernel<<<1, 1024, 0, stream>>>(cnt, off, N);
    fill_kernel<<<eb, 256, 0, stream>>>(src, dst, off, cursor, csr, E, N);

    int ab = (N * 32 + 255) / 256;   // aggregate: 32 lanes/node
    int lb = (N + 15) / 16;          // linear: 16 nodes/block
    int ob = (N * 64 + 255) / 256;   // out: 1 wave/node

    aggregate_kernel<<<ab, 256, 0, stream>>>(x, off, csr, agg, N);
    sage_linear_kernel<<<lb, 256, 0, stream>>>(agg, x, Wl0, Wr0, b0, h0, N);
    aggregate_kernel<<<ab, 256, 0, stream>>>(h0, off, csr, agg, N);
    sage_linear_kernel<<<lb, 256, 0, stream>>>(agg, h0, Wl1, Wr1, b1, h1, N);
    out_kernel<<<ob, 256, 0, stream>>>(h1, Wout, bout, (float*)d_out, N);
}

// Round 2
// 480.055 us; speedup vs baseline: 1.3087x; 1.3087x over previous
//
#include <hip/hip_runtime.h>

// GraphSAGE: 2x SAGEConv(mean) + Linear + softmax. fp32 throughout.
// Pipeline: CSR build (count / 3-phase scan / fill)
//           -> aggregate -> linear1(+ReLU) -> aggregate -> fused linear2+out+softmax.

#define CHUNK 2048   // elements per scan block (256 threads x 8)

__global__ void count_kernel(const int* __restrict__ dst, int* __restrict__ cnt, int E, int N) {
    int e = blockIdx.x * blockDim.x + threadIdx.x;
    if (e < E) {
        int d = dst[e];
        if ((unsigned)d < (unsigned)N) atomicAdd(&cnt[d], 1);
    }
}

// Phase A: per-chunk sums.
__global__ __launch_bounds__(256) void scan_partial_kernel(const int* __restrict__ cnt,
                                                           int* __restrict__ partial, int n) {
    __shared__ int ws[4];
    int base = blockIdx.x * CHUNK + (int)threadIdx.x * 8;
    int s = 0;
#pragma unroll
    for (int u = 0; u < 8; ++u) {
        int i = base + u;
        if (i < n) s += cnt[i];
    }
#pragma unroll
    for (int o = 32; o; o >>= 1) s += __shfl_xor(s, o, 64);
    int lane = threadIdx.x & 63, wv = threadIdx.x >> 6;
    if (lane == 0) ws[wv] = s;
    __syncthreads();
    if (threadIdx.x == 0) partial[blockIdx.x] = ws[0] + ws[1] + ws[2] + ws[3];
}

// Phase B: 1 wave scans the partials (P ~ 25), writes per-chunk bases + off[n].
__global__ void scan_base_kernel(const int* __restrict__ partial, int* __restrict__ baseArr,
                                 int* __restrict__ off, int P, int n) {
    int lane = threadIdx.x;   // blockDim = 64
    int running = 0;
    for (int b0 = 0; b0 < P; b0 += 64) {
        int i = b0 + lane;
        int v = (i < P) ? partial[i] : 0;
        int s = v;
#pragma unroll
        for (int o = 1; o < 64; o <<= 1) {
            int t = __shfl_up(s, o, 64);
            if (lane >= o) s += t;
        }
        if (i < P) baseArr[i] = running + s - v;
        running += __shfl(s, 63, 64);
    }
    if (lane == 0) off[n] = running;
}

// Phase C: per-chunk exclusive scan + base.
__global__ __launch_bounds__(256) void scan_chunk_kernel(const int* __restrict__ cnt,
                                                         const int* __restrict__ baseArr,
                                                         int* __restrict__ off, int n) {
    __shared__ int wsum[4];
    int lane = threadIdx.x & 63, wv = threadIdx.x >> 6;
    int i0 = blockIdx.x * CHUNK + (int)threadIdx.x * 8;
    int v[8];
    int ts = 0;
#pragma unroll
    for (int u = 0; u < 8; ++u) {
        int i = i0 + u;
        v[u] = (i < n) ? cnt[i] : 0;
        ts += v[u];
    }
    int s = ts;
#pragma unroll
    for (int o = 1; o < 64; o <<= 1) {
        int t = __shfl_up(s, o, 64);
        if (lane >= o) s += t;
    }
    if (lane == 63) wsum[wv] = s;
    __syncthreads();
    int run = baseArr[blockIdx.x];
    for (int w = 0; w < wv; ++w) run += wsum[w];
    run += s - ts;   // exclusive prefix for this thread's first element
#pragma unroll
    for (int u = 0; u < 8; ++u) {
        int i = i0 + u;
        if (i < n) off[i] = run;
        run += v[u];
    }
}

__global__ void fill_kernel(const int* __restrict__ src, const int* __restrict__ dstp,
                            const int* __restrict__ off, int* __restrict__ cursor,
                            int* __restrict__ csr, int E, int N) {
    int e = blockIdx.x * blockDim.x + threadIdx.x;
    if (e < E) {
        int d = dstp[e];
        int s = src[e];
        if ((unsigned)d < (unsigned)N) {
            int pos = atomicAdd(&cursor[d], 1);
            csr[off[d] + pos] = ((unsigned)s < (unsigned)N) ? s : 0;
        }
    }
}

// Mean aggregation: 32 lanes per node, float4 per lane, 2 independent accumulators.
__global__ void aggregate_kernel(const float* __restrict__ h, const int* __restrict__ off,
                                 const int* __restrict__ csr, float* __restrict__ agg, int N) {
    int t = blockIdx.x * blockDim.x + threadIdx.x;
    int node = t >> 5;
    int lane = t & 31;
    if (node >= N) return;
    int s0 = off[node], s1 = off[node + 1];
    const float4* h4 = (const float4*)h;
    float4 a0 = make_float4(0.f, 0.f, 0.f, 0.f);
    float4 a1 = make_float4(0.f, 0.f, 0.f, 0.f);
    int e = s0;
    for (; e + 2 <= s1; e += 2) {
        int i0 = csr[e], i1 = csr[e + 1];
        float4 v0 = h4[(size_t)i0 * 32 + lane];
        float4 v1 = h4[(size_t)i1 * 32 + lane];
        a0.x += v0.x; a0.y += v0.y; a0.z += v0.z; a0.w += v0.w;
        a1.x += v1.x; a1.y += v1.y; a1.z += v1.z; a1.w += v1.w;
    }
    if (e < s1) {
        int i0 = csr[e];
        float4 v0 = h4[(size_t)i0 * 32 + lane];
        a0.x += v0.x; a0.y += v0.y; a0.z += v0.z; a0.w += v0.w;
    }
    float inv = 1.0f / (float)max(s1 - s0, 1);
    ((float4*)agg)[(size_t)node * 32 + lane] = make_float4(
        (a0.x + a1.x) * inv, (a0.y + a1.y) * inv, (a0.z + a1.z) * inv, (a0.w + a1.w) * inv);
}

// hout = relu(agg @ Wl + hin @ Wr + b). Block: 32 nodes x 128 cols, 256 threads.
// Thread: column j for 16 nodes (g = node half). LDS feature reads are wave-broadcast b128.
__global__ __launch_bounds__(256) void sage_linear_kernel(
        const float* __restrict__ agg, const float* __restrict__ hin,
        const float* __restrict__ Wl, const float* __restrict__ Wr,
        const float* __restrict__ b, float* __restrict__ hout, int N) {
    __shared__ float sA[32][128];
    __shared__ float sB[32][128];
    int node0 = blockIdx.x * 32;
    const float4* agg4 = (const float4*)agg;
    const float4* hin4 = (const float4*)hin;
    for (int i = threadIdx.x; i < 32 * 32; i += 256) {   // float4 granularity
        int nn = i >> 5, f4 = i & 31;
        int node = node0 + nn;
        float4 a = make_float4(0.f, 0.f, 0.f, 0.f), hh = a;
        if (node < N) { a = agg4[(size_t)node * 32 + f4]; hh = hin4[(size_t)node * 32 + f4]; }
        ((float4*)sA[nn])[f4] = a;
        ((float4*)sB[nn])[f4] = hh;
    }
    __syncthreads();
    int j = threadIdx.x & 127;
    int g = threadIdx.x >> 7;   // 0 -> nodes 0..15, 1 -> nodes 16..31
    float acc[16];
    float bj = b[j];
#pragma unroll
    for (int q = 0; q < 16; ++q) acc[q] = bj;
    for (int k4 = 0; k4 < 32; ++k4) {
        float wl[4], wr[4];
#pragma unroll
        for (int u = 0; u < 4; ++u) {
            wl[u] = Wl[(k4 * 4 + u) * 128 + j];
            wr[u] = Wr[(k4 * 4 + u) * 128 + j];
        }
#pragma unroll
        for (int q = 0; q < 16; ++q) {
            int nn = g * 16 + q;
            float4 a = ((const float4*)sA[nn])[k4];
            float4 hh = ((const float4*)sB[nn])[k4];
            acc[q] += a.x * wl[0] + a.y * wl[1] + a.z * wl[2] + a.w * wl[3]
                    + hh.x * wr[0] + hh.y * wr[1] + hh.z * wr[2] + hh.w * wr[3];
        }
    }
#pragma unroll
    for (int q = 0; q < 16; ++q) {
        int node = node0 + g * 16 + q;
        if (node < N) hout[(size_t)node * 128 + j] = fmaxf(acc[q], 0.f);
    }
}

// Fused layer 2 + output projection + softmax:
// h1 = relu(agg @ Wl + hin @ Wr + b)  (32-node tile, kept in LDS)
// out = softmax(h1 @ Wout + bout)     (64 cols = 1 wave per node for shfl softmax)
__global__ __launch_bounds__(256) void sage_linear_out_kernel(
        const float* __restrict__ agg, const float* __restrict__ hin,
        const float* __restrict__ Wl, const float* __restrict__ Wr,
        const float* __restrict__ b, const float* __restrict__ Wout,
        const float* __restrict__ bout, float* __restrict__ out, int N) {
    __shared__ float sA[32][128];
    __shared__ float sB[32][128];
    int node0 = blockIdx.x * 32;
    const float4* agg4 = (const float4*)agg;
    const float4* hin4 = (const float4*)hin;
    for (int i = threadIdx.x; i < 32 * 32; i += 256) {
        int nn = i >> 5, f4 = i & 31;
        int node = node0 + nn;
        float4 a = make_float4(0.f, 0.f, 0.f, 0.f), hh = a;
        if (node < N) { a = agg4[(size_t)node * 32 + f4]; hh = hin4[(size_t)node * 32 + f4]; }
        ((float4*)sA[nn])[f4] = a;
        ((float4*)sB[nn])[f4] = hh;
    }
    __syncthreads();
    int j = threadIdx.x & 127;
    int g = threadIdx.x >> 7;
    float acc[16];
    float bj = b[j];
#pragma unroll
    for (int q = 0; q < 16; ++q) acc[q] = bj;
    for (int k4 = 0; k4 < 32; ++k4) {
        float wl[4], wr[4];
#pragma unroll
        for (int u = 0; u < 4; ++u) {
            wl[u] = Wl[(k4 * 4 + u) * 128 + j];
            wr[u] = Wr[(k4 * 4 + u) * 128 + j];
        }
#pragma unroll
        for (int q = 0; q < 16; ++q) {
            int nn = g * 16 + q;
            float4 a = ((const float4*)sA[nn])[k4];
            float4 hh = ((const float4*)sB[nn])[k4];
            acc[q] += a.x * wl[0] + a.y * wl[1] + a.z * wl[2] + a.w * wl[3]
                    + hh.x * wr[0] + hh.y * wr[1] + hh.z * wr[2] + hh.w * wr[3];
        }
    }
    __syncthreads();                          // everyone done reading sA/sB
#pragma unroll
    for (int q = 0; q < 16; ++q) sA[g * 16 + q][j] = fmaxf(acc[q], 0.f);   // h1 tile
    __syncthreads();

    // out stage: 64 cols; wave w handles nodes w*8..w*8+7, all 64 cols in-wave.
    int j2 = threadIdx.x & 63;
    int g2 = threadIdx.x >> 6;   // 0..3
    float o[8];
    float bo = bout[j2];
#pragma unroll
    for (int q = 0; q < 8; ++q) o[q] = bo;
    for (int k4 = 0; k4 < 32; ++k4) {
        float w[4];
#pragma unroll
        for (int u = 0; u < 4; ++u) w[u] = Wout[(k4 * 4 + u) * 64 + j2];
#pragma unroll
        for (int q = 0; q < 8; ++q) {
            float4 hv = ((const float4*)sA[g2 * 8 + q])[k4];
            o[q] += hv.x * w[0] + hv.y * w[1] + hv.z * w[2] + hv.w * w[3];
        }
    }
#pragma unroll
    for (int q = 0; q < 8; ++q) {
        float m = o[q];
#pragma unroll
        for (int ofs = 32; ofs; ofs >>= 1) m = fmaxf(m, __shfl_xor(m, ofs, 64));
        float e = __expf(o[q] - m);
        float s = e;
#pragma unroll
        for (int ofs = 32; ofs; ofs >>= 1) s += __shfl_xor(s, ofs, 64);
        int node = node0 + g2 * 8 + q;
        if (node < N) out[(size_t)node * 64 + j2] = e / s;
    }
}

extern "C" void kernel_launch(void* const* d_in, const int* in_sizes, int n_in,
                              void* d_out, int out_size, void* d_ws, size_t ws_size,
                              hipStream_t stream) {
    const float* x    = (const float*)d_in[0];
    const int*   ei   = (const int*)d_in[1];
    const float* Wl0  = (const float*)d_in[2];
    const float* Wr0  = (const float*)d_in[3];
    const float* b0   = (const float*)d_in[4];
    const float* Wl1  = (const float*)d_in[5];
    const float* Wr1  = (const float*)d_in[6];
    const float* b1   = (const float*)d_in[7];
    const float* Wout = (const float*)d_in[8];
    const float* bout = (const float*)d_in[9];

    int N = in_sizes[0] / 128;
    int E = in_sizes[1] / 2;
    const int* src = ei;
    const int* dst = ei + E;
    int P = (N + CHUNK - 1) / CHUNK;

    char* p = (char*)d_ws;
    auto alloc = [&](size_t bytes) -> char* {
        char* r = p;
        p += (bytes + 255) & ~(size_t)255;
        return r;
    };
    int*   cnt     = (int*)alloc((size_t)N * 4);
    int*   cursor  = (int*)alloc((size_t)N * 4);
    int*   off     = (int*)alloc((size_t)(N + 1) * 4);
    int*   csr     = (int*)alloc((size_t)E * 4);
    int*   partial = (int*)alloc((size_t)P * 4);
    int*   baseA   = (int*)alloc((size_t)P * 4);
    float* agg     = (float*)alloc((size_t)N * 128 * 4);
    float* h0      = (float*)alloc((size_t)N * 128 * 4);

    hipMemsetAsync(cnt, 0, (size_t)N * 4, stream);
    hipMemsetAsync(cursor, 0, (size_t)N * 4, stream);

    int eb = (E + 255) / 256;
    count_kernel<<<eb, 256, 0, stream>>>(dst, cnt, E, N);
    scan_partial_kernel<<<P, 256, 0, stream>>>(cnt, partial, N);
    scan_base_kernel<<<1, 64, 0, stream>>>(partial, baseA, off, P, N);
    scan_chunk_kernel<<<P, 256, 0, stream>>>(cnt, baseA, off, N);
    fill_kernel<<<eb, 256, 0, stream>>>(src, dst, off, cursor, csr, E, N);

    int ab = (N * 32 + 255) / 256;   // aggregate: 32 lanes/node
    int lb = (N + 31) / 32;          // linear: 32 nodes/block

    aggregate_kernel<<<ab, 256, 0, stream>>>(x, off, csr, agg, N);
    sage_linear_kernel<<<lb, 256, 0, stream>>>(agg, x, Wl0, Wr0, b0, h0, N);
    aggregate_kernel<<<ab, 256, 0, stream>>>(h0, off, csr, agg, N);
    sage_linear_out_kernel<<<lb, 256, 0, stream>>>(agg, h0, Wl1, Wr1, b1, Wout, bout,
                                                   (float*)d_out, N);
}